// Round 11
// baseline (213.216 us; speedup 1.0000x reference)
//
#include <hip/hip_runtime.h>
#include <stdint.h>

typedef unsigned short u16;
typedef uint32_t u32;
typedef __attribute__((ext_vector_type(8))) short bf16x8;
typedef __attribute__((ext_vector_type(4))) float f32x4;
typedef __attribute__((ext_vector_type(4))) u32 u32x4;

__device__ __forceinline__ u16 f2b(float x) {
  union { float f; uint32_t u; } v; v.f = x;
  uint32_t u = v.u;
  return (u16)((u + 0x7fffu + ((u >> 16) & 1u)) >> 16);
}

__device__ __forceinline__ float fexp2(float x) {
  float r;
  asm("v_exp_f32 %0, %1" : "=v"(r) : "v"(x));
  return r;
}

__device__ __forceinline__ u32 cvtpk(float lo, float hi) {
  u32 r;
  asm("v_cvt_pk_bf16_f32 %0, %1, %2" : "=v"(r) : "v"(lo), "v"(hi));
  return r;
}

__device__ __forceinline__ void gload_lds16(const void* g, void* l) {
  __builtin_amdgcn_global_load_lds(
      (const __attribute__((address_space(1))) void*)g,
      (__attribute__((address_space(3))) void*)l, 16, 0, 0);
}

// ---------------- fused f32 -> bf16 for q,k,v (one launch) ----------------
__global__ __launch_bounds__(256) void cvt3_f32_bf16(const float* __restrict__ q,
                                                     const float* __restrict__ k,
                                                     const float* __restrict__ v,
                                                     u16* __restrict__ xq,
                                                     u16* __restrict__ xk,
                                                     u16* __restrict__ xv, int n4) {
  int idx = blockIdx.x * 256 + threadIdx.x;
  if (idx >= n4) return;
  const int z = blockIdx.y;
  const float* in = z == 0 ? q : z == 1 ? k : v;
  u16* out = z == 0 ? xq : z == 1 ? xk : xv;
  float4 vv = ((const float4*)in)[idx];
  ushort4 o;
  o.x = f2b(vv.x); o.y = f2b(vv.y); o.z = f2b(vv.z); o.w = f2b(vv.w);
  ((ushort4*)out)[idx] = o;
}

// ---------------- transpose + convert: in (R,C) f32 -> out (C,R) bf16, z-select ----------------
__global__ __launch_bounds__(256) void transpose_cvt4(const float* __restrict__ w0,
                                                      const float* __restrict__ w1,
                                                      const float* __restrict__ w2,
                                                      const float* __restrict__ w3,
                                                      u16* __restrict__ o0,
                                                      u16* __restrict__ o1,
                                                      u16* __restrict__ o2,
                                                      u16* __restrict__ o3) {
  __shared__ float t[64][65];
  const int z = blockIdx.z;
  const float* inp = z == 0 ? w0 : z == 1 ? w1 : z == 2 ? w2 : w3;
  u16* outp = z == 0 ? o0 : z == 1 ? o1 : z == 2 ? o2 : o3;
  int r0 = blockIdx.x * 64, c0 = blockIdx.y * 64;
  for (int i = 0; i < 16; ++i) {
    int idx = i * 256 + threadIdx.x;
    int r = idx >> 6, c = idx & 63;
    t[r][c] = inp[(size_t)(r0 + r) * 1024 + (c0 + c)];
  }
  __syncthreads();
  for (int i = 0; i < 16; ++i) {
    int idx = i * 256 + threadIdx.x;
    int c = idx >> 6, r = idx & 63;
    outp[(size_t)(c0 + c) * 1024 + (r0 + r)] = f2b(t[r][c]);
  }
}

// gate_w: (16,64,64) f32 -> per-head transposed bf16 (h,e,d)
__global__ __launch_bounds__(256) void transpose_gate(const float* __restrict__ in,
                                                      u16* __restrict__ out) {
  __shared__ float t[64][65];
  const float* inp = in + (size_t)blockIdx.z * 4096;
  u16* outp = out + (size_t)blockIdx.z * 4096;
  for (int i = 0; i < 16; ++i) {
    int idx = i * 256 + threadIdx.x;
    int r = idx >> 6, c = idx & 63;
    t[r][c] = inp[(size_t)r * 64 + c];
  }
  __syncthreads();
  for (int i = 0; i < 16; ++i) {
    int idx = i * 256 + threadIdx.x;
    int c = idx >> 6, r = idx & 63;
    outp[(size_t)c * 64 + r] = f2b(t[r][c]);
  }
}

// ---------------- bf16 GEMM body: C = A(MxK) * Bt(NxK)^T + bias ----------------
// MODE 0: f32 out (M,N). MODE 1: bf16 split-head (b,h,t,d), scaled, bias on n.
// MODE 2: bf16 transposed-head (b,h,d,t): m = dim, n = token, bias on m.
template <int MODE>
__device__ __forceinline__ void gemm_body(const u16* __restrict__ A,
                                          const u16* __restrict__ Bt,
                                          const float* __restrict__ bias,
                                          void* __restrict__ Cout,
                                          int M, int N, int K, float scale,
                                          u16* lA, u16* lB, int bm, int bn) {
  const int tid = threadIdx.x;
  const int wave = tid >> 6, lane = tid & 63;
  const int l15 = lane & 15, l4 = lane >> 4;
  const int wr = (wave >> 1) * 64, wc = (wave & 1) * 64;
  f32x4 acc[4][4];
  for (int a = 0; a < 4; ++a)
    for (int b = 0; b < 4; ++b)
      for (int j = 0; j < 4; ++j) acc[a][b][j] = 0.f;
  const u16* Ab = A + (size_t)bm * 128 * K;
  const u16* Bb = Bt + (size_t)bn * 128 * K;
  for (int kt = 0; kt < K; kt += 64) {
    __syncthreads();
#pragma unroll
    for (int i = 0; i < 4; ++i) {
      int p = i * 256 + tid;
      int r = p >> 3, kc = p & 7, skc = kc ^ (r & 7);
      gload_lds16(Ab + (size_t)r * K + kt + skc * 8, &lA[p * 8]);
    }
#pragma unroll
    for (int i = 0; i < 4; ++i) {
      int p = i * 256 + tid;
      int r = p >> 3, kc = p & 7, skc = kc ^ (r & 7);
      gload_lds16(Bb + (size_t)r * K + kt + skc * 8, &lB[p * 8]);
    }
    __syncthreads();
#pragma unroll
    for (int kk = 0; kk < 2; ++kk) {
      const int kch = kk * 4 + l4;
      bf16x8 af[4], bfr[4];
#pragma unroll
      for (int mt = 0; mt < 4; ++mt) {
        int r = wr + mt * 16 + l15;
        af[mt] = *(const bf16x8*)&lA[r * 64 + ((kch ^ (r & 7)) << 3)];
      }
#pragma unroll
      for (int nt = 0; nt < 4; ++nt) {
        int r = wc + nt * 16 + l15;
        bfr[nt] = *(const bf16x8*)&lB[r * 64 + ((kch ^ (r & 7)) << 3)];
      }
      __builtin_amdgcn_s_setprio(1);
#pragma unroll
      for (int mt = 0; mt < 4; ++mt)
#pragma unroll
        for (int nt = 0; nt < 4; ++nt)
          acc[mt][nt] = __builtin_amdgcn_mfma_f32_16x16x32_bf16(af[mt], bfr[nt],
                                                                acc[mt][nt], 0, 0, 0);
      __builtin_amdgcn_s_setprio(0);
    }
  }
  float bval[4];
  float bvalm[4][4];
  if constexpr (MODE == 2) {
#pragma unroll
    for (int mt = 0; mt < 4; ++mt)
#pragma unroll
      for (int i = 0; i < 4; ++i)
        bvalm[mt][i] = bias[bm * 128 + wr + mt * 16 + l4 * 4 + i];
  } else {
#pragma unroll
    for (int nt = 0; nt < 4; ++nt) bval[nt] = bias[bn * 128 + wc + nt * 16 + l15];
  }
#pragma unroll
  for (int mt = 0; mt < 4; ++mt) {
#pragma unroll
    for (int nt = 0; nt < 4; ++nt) {
      int n = bn * 128 + wc + nt * 16 + l15;
#pragma unroll
      for (int i = 0; i < 4; ++i) {
        int m = bm * 128 + wr + mt * 16 + l4 * 4 + i;
        if constexpr (MODE == 0) {
          ((float*)Cout)[(size_t)m * N + n] = acc[mt][nt][i] + bval[nt];
        } else if constexpr (MODE == 1) {
          float v = acc[mt][nt][i] + bval[nt];
          int bb = m >> 11, t = m & 2047, hh = n >> 6, d = n & 63;
          ((u16*)Cout)[(((size_t)bb * 16 + hh) * 2048 + t) * 64 + d] = f2b(v * scale);
        } else {
          float v = acc[mt][nt][i] + bvalm[mt][i];
          int bb = n >> 11, t = n & 2047, hh = m >> 6, d = m & 63;
          ((u16*)Cout)[(((size_t)bb * 16 + hh) * 64 + d) * 2048 + t] = f2b(v);
        }
      }
    }
  }
}

// XCD-aware remap for 512-block GEMM grids: XCD x gets one 8-row chunk of the
// 64-axis x all 8 of the other axis -> A-panel (2 MB) + B-panels fit 4 MB L2.
__device__ __forceinline__ void gemm_swizzle(int& i64, int& i8) {
  int lid = blockIdx.x + (blockIdx.y << 6);  // 0..511, HW: xcd = lid & 7
  int xcd = lid & 7, s = lid >> 3;           // s = 0..63
  i64 = xcd * 8 + (s & 7);
  i8 = s >> 3;
}

// QKV projection: one dispatch; z=0 Q, z=1 K (split-head), z=2 V (transposed-head)
__global__ __launch_bounds__(256) void gemm_qkv(const u16* __restrict__ Xq,
                                                const u16* __restrict__ Xk,
                                                const u16* __restrict__ Xv,
                                                const u16* __restrict__ WqT,
                                                const u16* __restrict__ WkT,
                                                const u16* __restrict__ WvT,
                                                const float* __restrict__ bq,
                                                const float* __restrict__ bk,
                                                const float* __restrict__ bv,
                                                u16* __restrict__ Qb,
                                                u16* __restrict__ Kb,
                                                u16* __restrict__ Vtr, float qscale) {
  __shared__ __align__(16) u16 lA[128 * 64];
  __shared__ __align__(16) u16 lB[128 * 64];
  const int z = blockIdx.z;
  int i64, i8;
  gemm_swizzle(i64, i8);
  if (z == 2) {
    // V^T = WvT (M=1024 dims) x Xv^T (N=8192 tokens): out (b,h,d,t)
    gemm_body<2>(WvT, Xv, bv, Vtr, 1024, 8192, 1024, 1.0f, lA, lB, i8, i64);
  } else {
    const u16* A = z == 0 ? Xq : Xk;
    const u16* Bt = z == 0 ? WqT : WkT;
    const float* bias = z == 0 ? bq : bk;
    u16* C = z == 0 ? Qb : Kb;
    float scale = z == 0 ? qscale : 1.0f;
    gemm_body<1>(A, Bt, bias, C, 8192, 1024, 1024, scale, lA, lB, i64, i8);
  }
}

__global__ __launch_bounds__(256) void gemm_out(const u16* __restrict__ A,
                                                const u16* __restrict__ Bt,
                                                const float* __restrict__ bias,
                                                float* __restrict__ C) {
  __shared__ __align__(16) u16 lA[128 * 64];
  __shared__ __align__(16) u16 lB[128 * 64];
  int i64, i8;
  gemm_swizzle(i64, i8);
  gemm_body<0>(A, Bt, bias, C, 8192, 1024, 1024, 1.0f, lA, lB, i64, i8);
}

// ---------------- fused flash attention + per-head gate ----------------
// Swapped-operand: S^T = mfma(K,Q), PV^T = mfma(V^T,P^T); P = exp2(s) (no max).
// PHASE-STAGGER: tile sum is order-invariant, so each block visits KV tiles in
// a rotated order starting at t0 = f(block). Co-resident blocks are then in
// different {MFMA / VALU} phases -> both pipes fill instead of lockstep
// alternation (the invariant-100us bottleneck across r5-r9).
__global__ __launch_bounds__(256) void attn_fused(const u16* __restrict__ Qb,
                                                  const u16* __restrict__ Kb,
                                                  const u16* __restrict__ Vt,
                                                  const u16* __restrict__ GwT,
                                                  const float* __restrict__ gate_b,
                                                  u16* __restrict__ Yg) {
  // u16 elems: [0,4K)=Kbuf0 [4K,8K)=Kbuf1 [8K,12K)=Vbuf0 [12K,16K)=Vbuf1
  __shared__ __align__(16) u16 lds[16384];
  const int tid = threadIdx.x;
  const int w = tid >> 6, lane = tid & 63;
  const int l15 = lane & 15, l4 = lane >> 4;
  // XCD swizzle: HW assigns block i -> XCD i%8; XCD x owns bh in [8x,8x+8)
  const int bid = blockIdx.x;
  const int xcd = bid & 7, slot = bid >> 3;
  const int bh = xcd * 8 + (slot >> 4);
  const int qt = slot & 15;
  const int b = bh >> 4, h = bh & 15;
  // per-block tile rotation (phase stagger)
  const int t0 = (slot * 13) & 31;

  // Q fragments for two q-groups (B-operand: col=q=l15, k=d)
  const u16* QgA = Qb + ((size_t)bh * 2048 + qt * 128 + w * 32 + l15) * 64;
  const u16* QgB = QgA + 16 * 64;
  bf16x8 qA0 = *(const bf16x8*)(QgA + l4 * 8);
  bf16x8 qA1 = *(const bf16x8*)(QgA + 32 + l4 * 8);
  bf16x8 qB0 = *(const bf16x8*)(QgB + l4 * 8);
  bf16x8 qB1 = *(const bf16x8*)(QgB + 32 + l4 * 8);

  const bf16x8 ones = {0x3F80, 0x3F80, 0x3F80, 0x3F80, 0x3F80, 0x3F80, 0x3F80, 0x3F80};
  const f32x4 fz = {0.f, 0.f, 0.f, 0.f};

  f32x4 accA[4], accB[4], lsA, lsB;
#pragma unroll
  for (int nt = 0; nt < 4; ++nt)
#pragma unroll
    for (int j = 0; j < 4; ++j) { accA[nt][j] = 0.f; accB[nt][j] = 0.f; }
#pragma unroll
  for (int j = 0; j < 4; ++j) { lsA[j] = 0.f; lsB[j] = 0.f; }

  // fragment base pointers: xor term depends only on l15&7 -> 2 addr regs total
  const u16* f0 = lds + l15 * 64 + ((l4 ^ (l15 & 7)) << 3);        // kk=0 (kch=l4)
  const u16* f1 = lds + l15 * 64 + (((4 + l4) ^ (l15 & 7)) << 3);  // kk=1

  // staging pointers start at tile t0; wrap once past tile 31
  const int r0 = tid >> 3, kc0 = tid & 7, skc = kc0 ^ (r0 & 7);
  const int sr = ((r0 << 1) & 0x38) | ((r0 >> 3) & 4) | (r0 & 3);  // sigma(r)
  const u16* kp  = Kb + (size_t)bh * 131072 + (size_t)(t0 * 64 + sr) * 64 + skc * 8;
  const u16* kp2 = kp + 256;  // sigma(32+r) = sigma(r)+4 -> +4 rows
  const u16* vp  = Vt + (size_t)bh * 131072 + (size_t)r0 * 2048 + t0 * 64 + skc * 8;
  const u16* vp2 = vp + (size_t)32 * 2048;
  u16* dK = lds + tid * 8;
  u16* dV = lds + 8192 + tid * 8;
  int sc = 0;                       // tiles staged so far
  const int wrapN = 32 - t0;        // stage count after which pointers wrap

#define STAGE(c)                                                     \
  do {                                                               \
    gload_lds16(kp, dK + (c)*4096);                                  \
    gload_lds16(kp2, dK + (c)*4096 + 2048);                          \
    gload_lds16(vp, dV + (c)*4096);                                  \
    gload_lds16(vp2, dV + (c)*4096 + 2048);                          \
    kp += 4096; kp2 += 4096; vp += 64; vp2 += 64;                    \
    if (++sc == wrapN) {                                             \
      kp -= 131072; kp2 -= 131072; vp -= 2048; vp2 -= 2048;          \
    }                                                                \
  } while (0)

#define COMPUTE(c)                                                            \
  do {                                                                        \
    bf16x8 kf0[4], kf1[4];                                                    \
    _Pragma("unroll") for (int nt = 0; nt < 4; ++nt) {                        \
      kf0[nt] = *(const bf16x8*)(f0 + (c)*4096 + nt * 1024);                  \
      kf1[nt] = *(const bf16x8*)(f1 + (c)*4096 + nt * 1024);                  \
    }                                                                         \
    f32x4 sA[4], sB[4];                                                       \
    __builtin_amdgcn_s_setprio(1);                                            \
    _Pragma("unroll") for (int nt = 0; nt < 4; ++nt) {                        \
      sA[nt] = __builtin_amdgcn_mfma_f32_16x16x32_bf16(kf0[nt], qA0, fz, 0, 0, 0); \
      sA[nt] = __builtin_amdgcn_mfma_f32_16x16x32_bf16(kf1[nt], qA1, sA[nt], 0, 0, 0); \
      sB[nt] = __builtin_amdgcn_mfma_f32_16x16x32_bf16(kf0[nt], qB0, fz, 0, 0, 0); \
      sB[nt] = __builtin_amdgcn_mfma_f32_16x16x32_bf16(kf1[nt], qB1, sB[nt], 0, 0, 0); \
    }                                                                         \
    __builtin_amdgcn_s_setprio(0);                                            \
    union { u32x4 u; bf16x8 bv; } a0, a1, b0, b1;                             \
    a0.u[0] = cvtpk(fexp2(sA[0][0]), fexp2(sA[0][1]));                        \
    a0.u[1] = cvtpk(fexp2(sA[0][2]), fexp2(sA[0][3]));                        \
    a0.u[2] = cvtpk(fexp2(sA[2][0]), fexp2(sA[2][1]));                        \
    a0.u[3] = cvtpk(fexp2(sA[2][2]), fexp2(sA[2][3]));                        \
    a1.u[0] = cvtpk(fexp2(sA[1][0]), fexp2(sA[1][1]));                        \
    a1.u[1] = cvtpk(fexp2(sA[1][2]), fexp2(sA[1][3]));                        \
    a1.u[2] = cvtpk(fexp2(sA[3][0]), fexp2(sA[3][1]));                        \
    a1.u[3] = cvtpk(fexp2(sA[3][2]), fexp2(sA[3][3]));                        \
    b0.u[0] = cvtpk(fexp2(sB[0][0]), fexp2(sB[0][1]));                        \
    b0.u[1] = cvtpk(fexp2(sB[0][2]), fexp2(sB[0][3]));                        \
    b0.u[2] = cvtpk(fexp2(sB[2][0]), fexp2(sB[2][1]));                        \
    b0.u[3] = cvtpk(fexp2(sB[2][2]), fexp2(sB[2][3]));                        \
    b1.u[0] = cvtpk(fexp2(sB[1][0]), fexp2(sB[1][1]));                        \
    b1.u[1] = cvtpk(fexp2(sB[1][2]), fexp2(sB[1][3]));                        \
    b1.u[2] = cvtpk(fexp2(sB[3][0]), fexp2(sB[3][1]));                        \
    b1.u[3] = cvtpk(fexp2(sB[3][2]), fexp2(sB[3][3]));                        \
    __builtin_amdgcn_s_setprio(1);                                            \
    lsA = __builtin_amdgcn_mfma_f32_16x16x32_bf16(ones, a0.bv, lsA, 0, 0, 0); \
    lsA = __builtin_amdgcn_mfma_f32_16x16x32_bf16(ones, a1.bv, lsA, 0, 0, 0); \
    lsB = __builtin_amdgcn_mfma_f32_16x16x32_bf16(ones, b0.bv, lsB, 0, 0, 0); \
    lsB = __builtin_amdgcn_mfma_f32_16x16x32_bf16(ones, b1.bv, lsB, 0, 0, 0); \
    bf16x8 vf0[4], vf1[4];                                                    \
    _Pragma("unroll") for (int nt = 0; nt < 4; ++nt) {                        \
      vf0[nt] = *(const bf16x8*)(f0 + 8192 + (c)*4096 + nt * 1024);           \
      vf1[nt] = *(const bf16x8*)(f1 + 8192 + (c)*4096 + nt * 1024);           \
    }                                                                         \
    _Pragma("unroll") for (int nt = 0; nt < 4; ++nt) {                        \
      accA[nt] = __builtin_amdgcn_mfma_f32_16x16x32_bf16(vf0[nt], a0.bv, accA[nt], 0, 0, 0); \
      accA[nt] = __builtin_amdgcn_mfma_f32_16x16x32_bf16(vf1[nt], a1.bv, accA[nt], 0, 0, 0); \
      accB[nt] = __builtin_amdgcn_mfma_f32_16x16x32_bf16(vf0[nt], b0.bv, accB[nt], 0, 0, 0); \
      accB[nt] = __builtin_amdgcn_mfma_f32_16x16x32_bf16(vf1[nt], b1.bv, accB[nt], 0, 0, 0); \
    }                                                                         \
    __builtin_amdgcn_s_setprio(0);                                            \
  } while (0)

  STAGE(0);  // logical tile t0 -> buf0
  __syncthreads();
  for (int it = 0; it < 16; ++it) {
    STAGE(1);           // next tile -> buf1 (overlaps compute)
    COMPUTE(0);
    __syncthreads();
    if (it < 15) STAGE(0);
    COMPUTE(1);
    __syncthreads();
  }
#undef STAGE
#undef COMPUTE

  // ---- epilogue: normalize, gate, store (per q-group) ----
  bf16x8 gwf[2][4];
  {
    const u16* g = GwT + (size_t)h * 4096;
#pragma unroll
    for (int kk = 0; kk < 2; ++kk)
#pragma unroll
      for (int et = 0; et < 4; ++et)
        gwf[kk][et] = *(const bf16x8*)(g + (et * 16 + l15) * 64 + (kk * 4 + l4) * 8);
  }
  const float* gb = gate_b + h * 64;
  const int rsw = (l15 & 7) << 2;

#define EPILOGUE(accX, lsX, g)                                                 \
  do {                                                                         \
    float inv = 1.f / lsX[0];                                                  \
    float y[4][4];                                                             \
    _Pragma("unroll") for (int nt = 0; nt < 4; ++nt)                           \
      _Pragma("unroll") for (int i = 0; i < 4; ++i) y[nt][i] = accX[nt][i] * inv; \
    u32* ws32 = (u32*)lds + w * 2048 + (g)*1024;                               \
    _Pragma("unroll") for (int nt = 0; nt < 4; ++nt) {                         \
      u32 y0 = cvtpk(y[nt][0], y[nt][1]);                                      \
      u32 y1 = cvtpk(y[nt][2], y[nt][3]);                                      \
      int col = (nt * 8 + l4 * 2) ^ rsw;                                       \
      *(uint64_t*)(ws32 + l15 * 64 + col) = ((uint64_t)y1 << 32) | y0;         \
    }                                                                          \
    asm volatile("s_waitcnt lgkmcnt(0)" ::: "memory");                         \
    bf16x8 yf[2];                                                              \
    yf[0] = *(const bf16x8*)(ws32 + l15 * 64 + ((l4 * 4) ^ rsw));              \
    yf[1] = *(const bf16x8*)(ws32 + l15 * 64 + ((16 + l4 * 4) ^ rsw));         \
    f32x4 g4[4];                                                               \
    _Pragma("unroll") for (int et = 0; et < 4; ++et)                           \
      _Pragma("unroll") for (int j = 0; j < 4; ++j) g4[et][j] = 0.f;           \
    _Pragma("unroll") for (int kk = 0; kk < 2; ++kk)                           \
      _Pragma("unroll") for (int et = 0; et < 4; ++et)                         \
        g4[et] = __builtin_amdgcn_mfma_f32_16x16x32_bf16(gwf[kk][et], yf[kk], g4[et], 0, 0, 0); \
    u32 ok[4][2];                                                              \
    _Pragma("unroll") for (int et = 0; et < 4; ++et) {                         \
      float o[4];                                                              \
      _Pragma("unroll") for (int i = 0; i < 4; ++i) {                          \
        float gv = g4[et][i] + gb[et * 16 + l4 * 4 + i];                       \
        float sg = 1.f / (1.f + __expf(-gv));                                  \
        o[i] = y[et][i] * sg;                                                  \
      }                                                                        \
      ok[et][0] = cvtpk(o[0], o[1]);                                           \
      ok[et][1] = cvtpk(o[2], o[3]);                                           \
    }                                                                          \
    asm volatile("s_waitcnt lgkmcnt(0)" ::: "memory");                         \
    _Pragma("unroll") for (int et = 0; et < 4; ++et) {                         \
      int col = (et * 8 + l4 * 2) ^ rsw;                                       \
      *(uint64_t*)(ws32 + l15 * 64 + col) = ((uint64_t)ok[et][1] << 32) | ok[et][0]; \
    }                                                                          \
    asm volatile("s_waitcnt lgkmcnt(0)" ::: "memory");                         \
    {                                                                          \
      int rr = lane >> 2, c = lane & 3;                                        \
      int rs2 = (rr & 7) << 2;                                                 \
      u32x4 d0 = *(const u32x4*)(ws32 + rr * 64 + ((c * 4) ^ rs2));            \
      u32x4 d1 = *(const u32x4*)(ws32 + rr * 64 + (((c + 4) * 4) ^ rs2));      \
      size_t row = (size_t)b * 2048 + qt * 128 + w * 32 + (g)*16 + rr;         \
      u32* og = (u32*)(Yg + row * 1024 + h * 64);                              \
      *(u32x4*)(og + c * 4) = d0;                                              \
      *(u32x4*)(og + (c + 4) * 4) = d1;                                        \
    }                                                                          \
  } while (0)

  EPILOGUE(accA, lsA, 0);
  EPILOGUE(accB, lsB, 1);
#undef EPILOGUE
}

extern "C" void kernel_launch(void* const* d_in, const int* in_sizes, int n_in,
                              void* d_out, int out_size, void* d_ws, size_t ws_size,
                              hipStream_t stream) {
  (void)in_sizes; (void)n_in; (void)out_size; (void)ws_size;
  const float* query  = (const float*)d_in[0];
  const float* key    = (const float*)d_in[1];
  const float* value  = (const float*)d_in[2];
  const float* Wq     = (const float*)d_in[3];
  const float* bq     = (const float*)d_in[4];
  const float* Wk     = (const float*)d_in[5];
  const float* bk     = (const float*)d_in[6];
  const float* Wv     = (const float*)d_in[7];
  const float* bv     = (const float*)d_in[8];
  const float* Wo     = (const float*)d_in[9];
  const float* bo     = (const float*)d_in[10];
  const float* gate_w = (const float*)d_in[11];
  const float* gate_b = (const float*)d_in[12];

  const size_t XN = (size_t)8192 * 1024;
  const size_t WN = (size_t)1024 * 1024;
  char* ws = (char*)d_ws;
  size_t off = 0;
  auto nxt = [&](size_t bytes) {
    char* p = ws + off;
    off += (bytes + 255) & ~(size_t)255;
    return p;
  };
  u16* Xq  = (u16*)nxt(XN * 2);
  u16* Xk  = (u16*)nxt(XN * 2);
  u16* Xv  = (u16*)nxt(XN * 2);
  u16* WqT = (u16*)nxt(WN * 2);
  u16* WkT = (u16*)nxt(WN * 2);
  u16* WvT = (u16*)nxt(WN * 2);
  u16* WoT = (u16*)nxt(WN * 2);
  u16* GwT = (u16*)nxt((size_t)16 * 64 * 64 * 2);
  u16* Qb  = (u16*)nxt(XN * 2);
  u16* Kb  = (u16*)nxt(XN * 2);
  u16* Vtr = (u16*)nxt(XN * 2);
  u16* Yg  = (u16*)nxt(XN * 2);

  int n4 = (int)(XN / 4);
  cvt3_f32_bf16<<<dim3(n4 / 256, 3), 256, 0, stream>>>(query, key, value, Xq, Xk, Xv, n4);
  transpose_cvt4<<<dim3(16, 16, 4), 256, 0, stream>>>(Wq, Wk, Wv, Wo, WqT, WkT, WvT, WoT);
  transpose_gate<<<dim3(1, 1, 16), 256, 0, stream>>>(gate_w, GwT);

  // Q pre-scaled by 1/sqrt(D) * log2(e); V written directly transposed (b,h,d,t)
  gemm_qkv<<<dim3(64, 8, 3), 256, 0, stream>>>(Xq, Xk, Xv, WqT, WkT, WvT, bq, bk, bv,
                                               Qb, Kb, Vtr, 0.125f * 1.44269504f);
  attn_fused<<<1024, 256, 0, stream>>>(Qb, Kb, Vtr, GwT, gate_b, Yg);
  gemm_out<<<dim3(64, 8), 256, 0, stream>>>(Yg, WoT, bo, (float*)d_out);
}

// Round 12
// 202.598 us; speedup vs baseline: 1.0524x; 1.0524x over previous
//
#include <hip/hip_runtime.h>
#include <stdint.h>

typedef unsigned short u16;
typedef uint32_t u32;
typedef __attribute__((ext_vector_type(8))) short bf16x8;
typedef __attribute__((ext_vector_type(4))) float f32x4;
typedef __attribute__((ext_vector_type(4))) u32 u32x4;

__device__ __forceinline__ u16 f2b(float x) {
  union { float f; uint32_t u; } v; v.f = x;
  uint32_t u = v.u;
  return (u16)((u + 0x7fffu + ((u >> 16) & 1u)) >> 16);
}

__device__ __forceinline__ float fexp2(float x) {
  float r;
  asm("v_exp_f32 %0, %1" : "=v"(r) : "v"(x));
  return r;
}

__device__ __forceinline__ u32 cvtpk(float lo, float hi) {
  u32 r;
  asm("v_cvt_pk_bf16_f32 %0, %1, %2" : "=v"(r) : "v"(lo), "v"(hi));
  return r;
}

__device__ __forceinline__ void gload_lds16(const void* g, void* l) {
  __builtin_amdgcn_global_load_lds(
      (const __attribute__((address_space(1))) void*)g,
      (__attribute__((address_space(3))) void*)l, 16, 0, 0);
}

// ---------------- transpose + convert: in (R,C) f32 -> out (C,R) bf16, z-select ----------------
__global__ __launch_bounds__(256) void transpose_cvt4(const float* __restrict__ w0,
                                                      const float* __restrict__ w1,
                                                      const float* __restrict__ w2,
                                                      const float* __restrict__ w3,
                                                      u16* __restrict__ o0,
                                                      u16* __restrict__ o1,
                                                      u16* __restrict__ o2,
                                                      u16* __restrict__ o3) {
  __shared__ float t[64][65];
  const int z = blockIdx.z;
  const float* inp = z == 0 ? w0 : z == 1 ? w1 : z == 2 ? w2 : w3;
  u16* outp = z == 0 ? o0 : z == 1 ? o1 : z == 2 ? o2 : o3;
  int r0 = blockIdx.x * 64, c0 = blockIdx.y * 64;
  for (int i = 0; i < 16; ++i) {
    int idx = i * 256 + threadIdx.x;
    int r = idx >> 6, c = idx & 63;
    t[r][c] = inp[(size_t)(r0 + r) * 1024 + (c0 + c)];
  }
  __syncthreads();
  for (int i = 0; i < 16; ++i) {
    int idx = i * 256 + threadIdx.x;
    int c = idx >> 6, r = idx & 63;
    outp[(size_t)(c0 + c) * 1024 + (r0 + r)] = f2b(t[r][c]);
  }
}

// gate_w: (16,64,64) f32 -> per-head transposed bf16 (h,e,d)
__global__ __launch_bounds__(256) void transpose_gate(const float* __restrict__ in,
                                                      u16* __restrict__ out) {
  __shared__ float t[64][65];
  const float* inp = in + (size_t)blockIdx.z * 4096;
  u16* outp = out + (size_t)blockIdx.z * 4096;
  for (int i = 0; i < 16; ++i) {
    int idx = i * 256 + threadIdx.x;
    int r = idx >> 6, c = idx & 63;
    t[r][c] = inp[(size_t)r * 64 + c];
  }
  __syncthreads();
  for (int i = 0; i < 16; ++i) {
    int idx = i * 256 + threadIdx.x;
    int c = idx >> 6, r = idx & 63;
    outp[(size_t)c * 64 + r] = f2b(t[r][c]);
  }
}

// ---------------- bf16 GEMM body: C = A(MxK) * Bt(NxK)^T + bias ----------------
// MODE 0: f32 out (M,N). MODE 1: bf16 split-head (b,h,t,d), scaled, bias on n.
// MODE 2: bf16 transposed-head (b,h,d,t): m = dim, n = token, bias on m.
// AF32/BF32: operand is f32 in global memory; converted to bf16 during staging
// (reg-staged: float4 x2 -> cvt_pk_bf16 x4 -> ds_write_b128), fusing the input
// conversion pass into the GEMM.
template <int F32>
__device__ __forceinline__ void stage_tile(const void* __restrict__ base, int K,
                                           int kt, u16* ldst, int tid) {
#pragma unroll
  for (int i = 0; i < 4; ++i) {
    int p = i * 256 + tid;
    int r = p >> 3, kc = p & 7, skc = kc ^ (r & 7);
    if constexpr (F32) {
      const float* src = (const float*)base + (size_t)r * K + kt + skc * 8;
      float4 v0 = *(const float4*)src;
      float4 v1 = *(const float4*)(src + 4);
      u32x4 o;
      o[0] = cvtpk(v0.x, v0.y);
      o[1] = cvtpk(v0.z, v0.w);
      o[2] = cvtpk(v1.x, v1.y);
      o[3] = cvtpk(v1.z, v1.w);
      *(u32x4*)&ldst[p * 8] = o;
    } else {
      gload_lds16((const u16*)base + (size_t)r * K + kt + skc * 8, &ldst[p * 8]);
    }
  }
}

template <int MODE, int AF32, int BF32>
__device__ __forceinline__ void gemm_body(const void* __restrict__ A,
                                          const void* __restrict__ Bt,
                                          const float* __restrict__ bias,
                                          void* __restrict__ Cout,
                                          int M, int N, int K, float scale,
                                          u16* lA, u16* lB, int bm, int bn) {
  const int tid = threadIdx.x;
  const int wave = tid >> 6, lane = tid & 63;
  const int l15 = lane & 15, l4 = lane >> 4;
  const int wr = (wave >> 1) * 64, wc = (wave & 1) * 64;
  f32x4 acc[4][4];
  for (int a = 0; a < 4; ++a)
    for (int b = 0; b < 4; ++b)
      for (int j = 0; j < 4; ++j) acc[a][b][j] = 0.f;
  const char* Ab = (const char*)A + (size_t)bm * 128 * K * (AF32 ? 4 : 2);
  const char* Bb = (const char*)Bt + (size_t)bn * 128 * K * (BF32 ? 4 : 2);
  for (int kt = 0; kt < K; kt += 64) {
    __syncthreads();
    stage_tile<AF32>(Ab, K, kt, lA, tid);
    stage_tile<BF32>(Bb, K, kt, lB, tid);
    __syncthreads();
#pragma unroll
    for (int kk = 0; kk < 2; ++kk) {
      const int kch = kk * 4 + l4;
      bf16x8 af[4], bfr[4];
#pragma unroll
      for (int mt = 0; mt < 4; ++mt) {
        int r = wr + mt * 16 + l15;
        af[mt] = *(const bf16x8*)&lA[r * 64 + ((kch ^ (r & 7)) << 3)];
      }
#pragma unroll
      for (int nt = 0; nt < 4; ++nt) {
        int r = wc + nt * 16 + l15;
        bfr[nt] = *(const bf16x8*)&lB[r * 64 + ((kch ^ (r & 7)) << 3)];
      }
      __builtin_amdgcn_s_setprio(1);
#pragma unroll
      for (int mt = 0; mt < 4; ++mt)
#pragma unroll
        for (int nt = 0; nt < 4; ++nt)
          acc[mt][nt] = __builtin_amdgcn_mfma_f32_16x16x32_bf16(af[mt], bfr[nt],
                                                                acc[mt][nt], 0, 0, 0);
      __builtin_amdgcn_s_setprio(0);
    }
  }
  float bval[4];
  float bvalm[4][4];
  if constexpr (MODE == 2) {
#pragma unroll
    for (int mt = 0; mt < 4; ++mt)
#pragma unroll
      for (int i = 0; i < 4; ++i)
        bvalm[mt][i] = bias[bm * 128 + wr + mt * 16 + l4 * 4 + i];
  } else {
#pragma unroll
    for (int nt = 0; nt < 4; ++nt) bval[nt] = bias[bn * 128 + wc + nt * 16 + l15];
  }
#pragma unroll
  for (int mt = 0; mt < 4; ++mt) {
#pragma unroll
    for (int nt = 0; nt < 4; ++nt) {
      int n = bn * 128 + wc + nt * 16 + l15;
#pragma unroll
      for (int i = 0; i < 4; ++i) {
        int m = bm * 128 + wr + mt * 16 + l4 * 4 + i;
        if constexpr (MODE == 0) {
          ((float*)Cout)[(size_t)m * N + n] = acc[mt][nt][i] + bval[nt];
        } else if constexpr (MODE == 1) {
          float v = acc[mt][nt][i] + bval[nt];
          int bb = m >> 11, t = m & 2047, hh = n >> 6, d = n & 63;
          ((u16*)Cout)[(((size_t)bb * 16 + hh) * 2048 + t) * 64 + d] = f2b(v * scale);
        } else {
          float v = acc[mt][nt][i] + bvalm[mt][i];
          int bb = n >> 11, t = n & 2047, hh = m >> 6, d = m & 63;
          ((u16*)Cout)[(((size_t)bb * 16 + hh) * 64 + d) * 2048 + t] = f2b(v);
        }
      }
    }
  }
}

// XCD-aware remap for 512-block GEMM grids: XCD x gets one 8-row chunk of the
// 64-axis x all 8 of the other axis -> A-panel + B-panels mostly fit 4 MB L2.
__device__ __forceinline__ void gemm_swizzle(int& i64, int& i8) {
  int lid = blockIdx.x + (blockIdx.y << 6);  // 0..511, HW: xcd = lid & 7
  int xcd = lid & 7, s = lid >> 3;           // s = 0..63
  i64 = xcd * 8 + (s & 7);
  i8 = s >> 3;
}

// QKV projection: one dispatch; z=0 Q, z=1 K (split-head), z=2 V (transposed-head)
// Inputs query/key/value are f32 -- converted to bf16 inside the staging.
__global__ __launch_bounds__(256) void gemm_qkv(const float* __restrict__ Xq,
                                                const float* __restrict__ Xk,
                                                const float* __restrict__ Xv,
                                                const u16* __restrict__ WqT,
                                                const u16* __restrict__ WkT,
                                                const u16* __restrict__ WvT,
                                                const float* __restrict__ bq,
                                                const float* __restrict__ bk,
                                                const float* __restrict__ bv,
                                                u16* __restrict__ Qb,
                                                u16* __restrict__ Kb,
                                                u16* __restrict__ Vtr, float qscale) {
  __shared__ __align__(16) u16 lA[128 * 64];
  __shared__ __align__(16) u16 lB[128 * 64];
  const int z = blockIdx.z;
  int i64, i8;
  gemm_swizzle(i64, i8);
  if (z == 2) {
    // V^T = WvT (M=1024 dims) x Xv^T (N=8192 tokens): out (b,h,d,t)
    gemm_body<2, 0, 1>(WvT, Xv, bv, Vtr, 1024, 8192, 1024, 1.0f, lA, lB, i8, i64);
  } else if (z == 0) {
    gemm_body<1, 1, 0>(Xq, WqT, bq, Qb, 8192, 1024, 1024, qscale, lA, lB, i64, i8);
  } else {
    gemm_body<1, 1, 0>(Xk, WkT, bk, Kb, 8192, 1024, 1024, 1.0f, lA, lB, i64, i8);
  }
}

__global__ __launch_bounds__(256) void gemm_out(const u16* __restrict__ A,
                                                const u16* __restrict__ Bt,
                                                const float* __restrict__ bias,
                                                float* __restrict__ C) {
  __shared__ __align__(16) u16 lA[128 * 64];
  __shared__ __align__(16) u16 lB[128 * 64];
  int i64, i8;
  gemm_swizzle(i64, i8);
  gemm_body<0, 0, 0>(A, Bt, bias, C, 8192, 1024, 1024, 1.0f, lA, lB, i64, i8);
}

// ---------------- fused flash attention + per-head gate ----------------
// Swapped-operand: S^T = mfma(K,Q), PV^T = mfma(V^T,P^T); P = exp2(s) (no max:
// scores tiny, softmax shift-invariant); row-sums on MFMA pipe via mfma(ones,P).
// 32 q-rows/wave sharing K/V fragment reads. XCD-aware block mapping: XCD x
// owns bh in [8x, 8x+8) -> K/V working set L2-resident (FETCH 140->25 MB, r8).
__global__ __launch_bounds__(256) void attn_fused(const u16* __restrict__ Qb,
                                                  const u16* __restrict__ Kb,
                                                  const u16* __restrict__ Vt,
                                                  const u16* __restrict__ GwT,
                                                  const float* __restrict__ gate_b,
                                                  u16* __restrict__ Yg) {
  // u16 elems: [0,4K)=Kbuf0 [4K,8K)=Kbuf1 [8K,12K)=Vbuf0 [12K,16K)=Vbuf1
  __shared__ __align__(16) u16 lds[16384];
  const int tid = threadIdx.x;
  const int w = tid >> 6, lane = tid & 63;
  const int l15 = lane & 15, l4 = lane >> 4;
  // XCD swizzle: HW assigns block i -> XCD i%8; XCD x owns bh in [8x,8x+8)
  const int bid = blockIdx.x;
  const int xcd = bid & 7, slot = bid >> 3;
  const int bh = xcd * 8 + (slot >> 4);
  const int qt = slot & 15;
  const int b = bh >> 4, h = bh & 15;

  // Q fragments for two q-groups (B-operand: col=q=l15, k=d)
  const u16* QgA = Qb + ((size_t)bh * 2048 + qt * 128 + w * 32 + l15) * 64;
  const u16* QgB = QgA + 16 * 64;
  bf16x8 qA0 = *(const bf16x8*)(QgA + l4 * 8);
  bf16x8 qA1 = *(const bf16x8*)(QgA + 32 + l4 * 8);
  bf16x8 qB0 = *(const bf16x8*)(QgB + l4 * 8);
  bf16x8 qB1 = *(const bf16x8*)(QgB + 32 + l4 * 8);

  const bf16x8 ones = {0x3F80, 0x3F80, 0x3F80, 0x3F80, 0x3F80, 0x3F80, 0x3F80, 0x3F80};
  const f32x4 fz = {0.f, 0.f, 0.f, 0.f};

  f32x4 accA[4], accB[4], lsA, lsB;
#pragma unroll
  for (int nt = 0; nt < 4; ++nt)
#pragma unroll
    for (int j = 0; j < 4; ++j) { accA[nt][j] = 0.f; accB[nt][j] = 0.f; }
#pragma unroll
  for (int j = 0; j < 4; ++j) { lsA[j] = 0.f; lsB[j] = 0.f; }

  // fragment base pointers: xor term depends only on l15&7 -> 2 addr regs total
  const u16* f0 = lds + l15 * 64 + ((l4 ^ (l15 & 7)) << 3);        // kk=0 (kch=l4)
  const u16* f1 = lds + l15 * 64 + (((4 + l4) ^ (l15 & 7)) << 3);  // kk=1

  // staging pointers (advanced per tile); second K row-block = rows sr+4
  const int r0 = tid >> 3, kc0 = tid & 7, skc = kc0 ^ (r0 & 7);
  const int sr = ((r0 << 1) & 0x38) | ((r0 >> 3) & 4) | (r0 & 3);  // sigma(r)
  const u16* kp  = Kb + (size_t)bh * 131072 + (size_t)sr * 64 + skc * 8;
  const u16* kp2 = kp + 256;  // sigma(32+r) = sigma(r)+4 -> +4 rows = +256 u16
  const u16* vp  = Vt + (size_t)bh * 131072 + (size_t)r0 * 2048 + skc * 8;
  const u16* vp2 = vp + (size_t)32 * 2048;
  u16* dK = lds + tid * 8;
  u16* dV = lds + 8192 + tid * 8;

#define STAGE(c)                                                     \
  do {                                                               \
    gload_lds16(kp, dK + (c)*4096);                                  \
    gload_lds16(kp2, dK + (c)*4096 + 2048);                          \
    gload_lds16(vp, dV + (c)*4096);                                  \
    gload_lds16(vp2, dV + (c)*4096 + 2048);                          \
    kp += 4096; kp2 += 4096; vp += 64; vp2 += 64;                    \
  } while (0)

#define COMPUTE(c)                                                            \
  do {                                                                        \
    bf16x8 kf0[4], kf1[4];                                                    \
    _Pragma("unroll") for (int nt = 0; nt < 4; ++nt) {                        \
      kf0[nt] = *(const bf16x8*)(f0 + (c)*4096 + nt * 1024);                  \
      kf1[nt] = *(const bf16x8*)(f1 + (c)*4096 + nt * 1024);                  \
    }                                                                         \
    f32x4 sA[4], sB[4];                                                       \
    __builtin_amdgcn_s_setprio(1);                                            \
    _Pragma("unroll") for (int nt = 0; nt < 4; ++nt) {                        \
      sA[nt] = __builtin_amdgcn_mfma_f32_16x16x32_bf16(kf0[nt], qA0, fz, 0, 0, 0); \
      sA[nt] = __builtin_amdgcn_mfma_f32_16x16x32_bf16(kf1[nt], qA1, sA[nt], 0, 0, 0); \
      sB[nt] = __builtin_amdgcn_mfma_f32_16x16x32_bf16(kf0[nt], qB0, fz, 0, 0, 0); \
      sB[nt] = __builtin_amdgcn_mfma_f32_16x16x32_bf16(kf1[nt], qB1, sB[nt], 0, 0, 0); \
    }                                                                         \
    __builtin_amdgcn_s_setprio(0);                                            \
    union { u32x4 u; bf16x8 bv; } a0, a1, b0, b1;                             \
    a0.u[0] = cvtpk(fexp2(sA[0][0]), fexp2(sA[0][1]));                        \
    a0.u[1] = cvtpk(fexp2(sA[0][2]), fexp2(sA[0][3]));                        \
    a0.u[2] = cvtpk(fexp2(sA[2][0]), fexp2(sA[2][1]));                        \
    a0.u[3] = cvtpk(fexp2(sA[2][2]), fexp2(sA[2][3]));                        \
    a1.u[0] = cvtpk(fexp2(sA[1][0]), fexp2(sA[1][1]));                        \
    a1.u[1] = cvtpk(fexp2(sA[1][2]), fexp2(sA[1][3]));                        \
    a1.u[2] = cvtpk(fexp2(sA[3][0]), fexp2(sA[3][1]));                        \
    a1.u[3] = cvtpk(fexp2(sA[3][2]), fexp2(sA[3][3]));                        \
    b0.u[0] = cvtpk(fexp2(sB[0][0]), fexp2(sB[0][1]));                        \
    b0.u[1] = cvtpk(fexp2(sB[0][2]), fexp2(sB[0][3]));                        \
    b0.u[2] = cvtpk(fexp2(sB[2][0]), fexp2(sB[2][1]));                        \
    b0.u[3] = cvtpk(fexp2(sB[2][2]), fexp2(sB[2][3]));                        \
    b1.u[0] = cvtpk(fexp2(sB[1][0]), fexp2(sB[1][1]));                        \
    b1.u[1] = cvtpk(fexp2(sB[1][2]), fexp2(sB[1][3]));                        \
    b1.u[2] = cvtpk(fexp2(sB[3][0]), fexp2(sB[3][1]));                        \
    b1.u[3] = cvtpk(fexp2(sB[3][2]), fexp2(sB[3][3]));                        \
    __builtin_amdgcn_s_setprio(1);                                            \
    lsA = __builtin_amdgcn_mfma_f32_16x16x32_bf16(ones, a0.bv, lsA, 0, 0, 0); \
    lsA = __builtin_amdgcn_mfma_f32_16x16x32_bf16(ones, a1.bv, lsA, 0, 0, 0); \
    lsB = __builtin_amdgcn_mfma_f32_16x16x32_bf16(ones, b0.bv, lsB, 0, 0, 0); \
    lsB = __builtin_amdgcn_mfma_f32_16x16x32_bf16(ones, b1.bv, lsB, 0, 0, 0); \
    bf16x8 vf0[4], vf1[4];                                                    \
    _Pragma("unroll") for (int nt = 0; nt < 4; ++nt) {                        \
      vf0[nt] = *(const bf16x8*)(f0 + 8192 + (c)*4096 + nt * 1024);           \
      vf1[nt] = *(const bf16x8*)(f1 + 8192 + (c)*4096 + nt * 1024);           \
    }                                                                         \
    _Pragma("unroll") for (int nt = 0; nt < 4; ++nt) {                        \
      accA[nt] = __builtin_amdgcn_mfma_f32_16x16x32_bf16(vf0[nt], a0.bv, accA[nt], 0, 0, 0); \
      accA[nt] = __builtin_amdgcn_mfma_f32_16x16x32_bf16(vf1[nt], a1.bv, accA[nt], 0, 0, 0); \
      accB[nt] = __builtin_amdgcn_mfma_f32_16x16x32_bf16(vf0[nt], b0.bv, accB[nt], 0, 0, 0); \
      accB[nt] = __builtin_amdgcn_mfma_f32_16x16x32_bf16(vf1[nt], b1.bv, accB[nt], 0, 0, 0); \
    }                                                                         \
    __builtin_amdgcn_s_setprio(0);                                            \
  } while (0)

  STAGE(0);  // tile 0 -> buf0
  __syncthreads();
  for (int it = 0; it < 16; ++it) {
    STAGE(1);           // tile 2it+1 -> buf1 (overlaps compute)
    COMPUTE(0);         // tile 2it
    __syncthreads();
    if (it < 15) STAGE(0);  // tile 2it+2 -> buf0
    COMPUTE(1);         // tile 2it+1
    __syncthreads();
  }
#undef STAGE
#undef COMPUTE

  // ---- epilogue: normalize, gate, store (per q-group) ----
  bf16x8 gwf[2][4];
  {
    const u16* g = GwT + (size_t)h * 4096;
#pragma unroll
    for (int kk = 0; kk < 2; ++kk)
#pragma unroll
      for (int et = 0; et < 4; ++et)
        gwf[kk][et] = *(const bf16x8*)(g + (et * 16 + l15) * 64 + (kk * 4 + l4) * 8);
  }
  const float* gb = gate_b + h * 64;
  const int rsw = (l15 & 7) << 2;

#define EPILOGUE(accX, lsX, g)                                                 \
  do {                                                                         \
    float inv = 1.f / lsX[0];                                                  \
    float y[4][4];                                                             \
    _Pragma("unroll") for (int nt = 0; nt < 4; ++nt)                           \
      _Pragma("unroll") for (int i = 0; i < 4; ++i) y[nt][i] = accX[nt][i] * inv; \
    u32* ws32 = (u32*)lds + w * 2048 + (g)*1024;                               \
    _Pragma("unroll") for (int nt = 0; nt < 4; ++nt) {                         \
      u32 y0 = cvtpk(y[nt][0], y[nt][1]);                                      \
      u32 y1 = cvtpk(y[nt][2], y[nt][3]);                                      \
      int col = (nt * 8 + l4 * 2) ^ rsw;                                       \
      *(uint64_t*)(ws32 + l15 * 64 + col) = ((uint64_t)y1 << 32) | y0;         \
    }                                                                          \
    asm volatile("s_waitcnt lgkmcnt(0)" ::: "memory");                         \
    bf16x8 yf[2];                                                              \
    yf[0] = *(const bf16x8*)(ws32 + l15 * 64 + ((l4 * 4) ^ rsw));              \
    yf[1] = *(const bf16x8*)(ws32 + l15 * 64 + ((16 + l4 * 4) ^ rsw));         \
    f32x4 g4[4];                                                               \
    _Pragma("unroll") for (int et = 0; et < 4; ++et)                           \
      _Pragma("unroll") for (int j = 0; j < 4; ++j) g4[et][j] = 0.f;           \
    _Pragma("unroll") for (int kk = 0; kk < 2; ++kk)                           \
      _Pragma("unroll") for (int et = 0; et < 4; ++et)                         \
        g4[et] = __builtin_amdgcn_mfma_f32_16x16x32_bf16(gwf[kk][et], yf[kk], g4[et], 0, 0, 0); \
    u32 ok[4][2];                                                              \
    _Pragma("unroll") for (int et = 0; et < 4; ++et) {                         \
      float o[4];                                                              \
      _Pragma("unroll") for (int i = 0; i < 4; ++i) {                          \
        float gv = g4[et][i] + gb[et * 16 + l4 * 4 + i];                       \
        float sg = 1.f / (1.f + __expf(-gv));                                  \
        o[i] = y[et][i] * sg;                                                  \
      }                                                                        \
      ok[et][0] = cvtpk(o[0], o[1]);                                           \
      ok[et][1] = cvtpk(o[2], o[3]);                                           \
    }                                                                          \
    asm volatile("s_waitcnt lgkmcnt(0)" ::: "memory");                         \
    _Pragma("unroll") for (int et = 0; et < 4; ++et) {                         \
      int col = (et * 8 + l4 * 2) ^ rsw;                                       \
      *(uint64_t*)(ws32 + l15 * 64 + col) = ((uint64_t)ok[et][1] << 32) | ok[et][0]; \
    }                                                                          \
    asm volatile("s_waitcnt lgkmcnt(0)" ::: "memory");                         \
    {                                                                          \
      int rr = lane >> 2, c = lane & 3;                                        \
      int rs2 = (rr & 7) << 2;                                                 \
      u32x4 d0 = *(const u32x4*)(ws32 + rr * 64 + ((c * 4) ^ rs2));            \
      u32x4 d1 = *(const u32x4*)(ws32 + rr * 64 + (((c + 4) * 4) ^ rs2));      \
      size_t row = (size_t)b * 2048 + qt * 128 + w * 32 + (g)*16 + rr;         \
      u32* og = (u32*)(Yg + row * 1024 + h * 64);                              \
      *(u32x4*)(og + c * 4) = d0;                                              \
      *(u32x4*)(og + (c + 4) * 4) = d1;                                        \
    }                                                                          \
  } while (0)

  EPILOGUE(accA, lsA, 0);
  EPILOGUE(accB, lsB, 1);
#undef EPILOGUE
}

extern "C" void kernel_launch(void* const* d_in, const int* in_sizes, int n_in,
                              void* d_out, int out_size, void* d_ws, size_t ws_size,
                              hipStream_t stream) {
  (void)in_sizes; (void)n_in; (void)out_size; (void)ws_size;
  const float* query  = (const float*)d_in[0];
  const float* key    = (const float*)d_in[1];
  const float* value  = (const float*)d_in[2];
  const float* Wq     = (const float*)d_in[3];
  const float* bq     = (const float*)d_in[4];
  const float* Wk     = (const float*)d_in[5];
  const float* bk     = (const float*)d_in[6];
  const float* Wv     = (const float*)d_in[7];
  const float* bv     = (const float*)d_in[8];
  const float* Wo     = (const float*)d_in[9];
  const float* bo     = (const float*)d_in[10];
  const float* gate_w = (const float*)d_in[11];
  const float* gate_b = (const float*)d_in[12];

  const size_t XN = (size_t)8192 * 1024;
  const size_t WN = (size_t)1024 * 1024;
  char* ws = (char*)d_ws;
  size_t off = 0;
  auto nxt = [&](size_t bytes) {
    char* p = ws + off;
    off += (bytes + 255) & ~(size_t)255;
    return p;
  };
  u16* WqT = (u16*)nxt(WN * 2);
  u16* WkT = (u16*)nxt(WN * 2);
  u16* WvT = (u16*)nxt(WN * 2);
  u16* WoT = (u16*)nxt(WN * 2);
  u16* GwT = (u16*)nxt((size_t)16 * 64 * 64 * 2);
  u16* Qb  = (u16*)nxt(XN * 2);
  u16* Kb  = (u16*)nxt(XN * 2);
  u16* Vtr = (u16*)nxt(XN * 2);
  u16* Yg  = (u16*)nxt(XN * 2);

  transpose_cvt4<<<dim3(16, 16, 4), 256, 0, stream>>>(Wq, Wk, Wv, Wo, WqT, WkT, WvT, WoT);
  transpose_gate<<<dim3(1, 1, 16), 256, 0, stream>>>(gate_w, GwT);

  // Q pre-scaled by 1/sqrt(D) * log2(e); V written directly transposed (b,h,d,t);
  // f32->bf16 conversion of query/key/value fused into the GEMM staging.
  gemm_qkv<<<dim3(64, 8, 3), 256, 0, stream>>>(query, key, value, WqT, WkT, WvT,
                                               bq, bk, bv, Qb, Kb, Vtr,
                                               0.125f * 1.44269504f);
  attn_fused<<<1024, 256, 0, stream>>>(Qb, Kb, Vtr, GwT, gate_b, Yg);
  gemm_out<<<dim3(64, 8), 256, 0, stream>>>(Yg, WoT, bo, (float*)d_out);
}